// Round 1
// baseline (419.073 us; speedup 1.0000x reference)
//
#include <hip/hip_runtime.h>
#include <cstddef>
#include <cstdint>

#define LOG2E 1.4426950408889634f

// ---------------- helpers ----------------
__device__ __forceinline__ float readlane_f(float v, int l) {
  return __int_as_float(__builtin_amdgcn_readlane(__float_as_int(v), l));
}
template<int CTRL>
__device__ __forceinline__ float dpp_add(float x) {
  int y = __builtin_amdgcn_update_dpp(0, __float_as_int(x), CTRL, 0xF, 0xF, false);
  return x + __int_as_float(y);
}
// full 64-lane sum; valid in lane 63 (row_shr 1,2,4,8 then bcast15, bcast31)
__device__ __forceinline__ float wave_sum64(float p) {
  p = dpp_add<0x111>(p); p = dpp_add<0x112>(p); p = dpp_add<0x114>(p);
  p = dpp_add<0x118>(p); p = dpp_add<0x142>(p); p = dpp_add<0x143>(p);
  return p;
}
__device__ __forceinline__ float silu_f(float x) {
  return x * __builtin_amdgcn_rcpf(1.f + __builtin_amdgcn_exp2f(-x * LOG2E));
}
// quaternion sign: negatives at (ic,oc) in {(1,0),(2,0),(3,0),(1,2),(3,1),(2,3)}
__device__ __forceinline__ float qsign(int ic, int oc) {
  return ((0x3950u >> (ic * 4 + oc)) & 1u) ? -1.f : 1.f;
}

// ---------------- WT prep: transpose xproj_W [1024,136] -> WT [136,1024] ----
__global__ __launch_bounds__(256) void wtprep_kernel(const float* __restrict__ W,
                                                     float* __restrict__ WT) {
  int c = blockIdx.x;                       // 0..135
  int k = blockIdx.y * 256 + threadIdx.x;   // 0..1023
  WT[c * 1024 + k] = W[k * 136 + c];
}

// ---------------- gemm_in: xz[m, 0:2048] = X4[m,0:512] @ Wq -----------------
// tile 128(M) x 64(N), KC=16, block 128 threads, 8x8 per thread, K-split 2.
__global__ __launch_bounds__(128) void gemm_in_kernel(
    const float* __restrict__ q0, const float* __restrict__ q1,
    const float* __restrict__ q2, const float* __restrict__ q3,
    const float* __restrict__ w0, const float* __restrict__ w1,
    const float* __restrict__ w2, const float* __restrict__ w3,
    float* __restrict__ out0, float* __restrict__ out1) {
  __shared__ float As[16][128];
  __shared__ float Bs[16][64];
  const int tid = threadIdx.x;
  const int m0 = blockIdx.x * 128;
  const int n0 = blockIdx.y * 64;
  const int kbase = blockIdx.z * 256;
  const int oc = n0 >> 9;
  const int col0 = n0 & 511;
  const int tm = tid & 15, tn = tid >> 4;
  float acc[8][8] = {};
  for (int kc = 0; kc < 256; kc += 16) {
    const int k0 = kbase + kc;
    const int c = k0 >> 7;
    const int kin = k0 & 127;
    const float* Q = (c == 0) ? q0 : (c == 1) ? q1 : (c == 2) ? q2 : q3;
    const int wi = c ^ oc;
    const float* W = (wi == 0) ? w0 : (wi == 1) ? w1 : (wi == 2) ? w2 : w3;
    const float sg = qsign(c, oc);
    // stage A: As[kk][mm] = Q[(m0+mm)*128 + kin + kk]
#pragma unroll
    for (int j = 0; j < 4; ++j) {
      int fidx = tid + j * 128;            // 0..511
      int mm = fidx >> 2, kq = fidx & 3;
      const float4 v = *(const float4*)&Q[(size_t)(m0 + mm) * 128 + kin + kq * 4];
      As[kq * 4 + 0][mm] = v.x; As[kq * 4 + 1][mm] = v.y;
      As[kq * 4 + 2][mm] = v.z; As[kq * 4 + 3][mm] = v.w;
    }
    // stage B: Bs[kk][nn] = sg * W[(kin+kk)*512 + col0 + nn]
#pragma unroll
    for (int j = 0; j < 2; ++j) {
      int fidx = tid + j * 128;            // 0..255
      int kk = fidx >> 4, nq = fidx & 15;
      float4 v = *(const float4*)&W[(size_t)(kin + kk) * 512 + col0 + nq * 4];
      v.x *= sg; v.y *= sg; v.z *= sg; v.w *= sg;
      *(float4*)&Bs[kk][nq * 4] = v;
    }
    __syncthreads();
#pragma unroll
    for (int kk = 0; kk < 16; ++kk) {
      float a[8], bb[8];
      *(float4*)&a[0] = *(const float4*)&As[kk][tm * 8];
      *(float4*)&a[4] = *(const float4*)&As[kk][tm * 8 + 4];
      *(float4*)&bb[0] = *(const float4*)&Bs[kk][tn * 8];
      *(float4*)&bb[4] = *(const float4*)&Bs[kk][tn * 8 + 4];
#pragma unroll
      for (int u = 0; u < 8; ++u)
#pragma unroll
        for (int v = 0; v < 8; ++v) acc[u][v] = fmaf(a[u], bb[v], acc[u][v]);
    }
    __syncthreads();
  }
  float* dst = (blockIdx.z == 0) ? out0 : out1;
#pragma unroll
  for (int u = 0; u < 8; ++u) {
    size_t m = (size_t)(m0 + tm * 8 + u);
    *(float4*)&dst[m * 2048 + n0 + tn * 8] =
        make_float4(acc[u][0], acc[u][1], acc[u][2], acc[u][3]);
    *(float4*)&dst[m * 2048 + n0 + tn * 8 + 4] =
        make_float4(acc[u][4], acc[u][5], acc[u][6], acc[u][7]);
  }
}

// ---------------- conv: causal depthwise conv(4)+bias+SiLU; writes xT -------
__global__ __launch_bounds__(256) void conv_kernel(
    const float* __restrict__ xz0, const float* __restrict__ xz1,
    const float* __restrict__ conv_w, const float* __restrict__ conv_b,
    float* __restrict__ xT) {
  __shared__ float X[67][65];
  __shared__ float Wl[256];
  __shared__ float Bi[64];
  const int tid = threadIdx.x;
  const int t0 = blockIdx.x * 64;
  const int d0 = blockIdx.y * 64;
  const int b = blockIdx.z;
  Wl[tid] = conv_w[d0 * 4 + tid];
  if (tid < 64) Bi[tid] = conv_b[d0 + tid];
  for (int idx = tid; idx < 67 * 64; idx += 256) {
    int tl = idx >> 6, dl = idx & 63;
    int t = t0 - 3 + tl;
    float v = 0.f;
    if (t >= 0) {
      size_t o = ((size_t)(b * 1024 + t)) * 2048 + d0 + dl;
      v = xz0[o] + xz1[o];
    }
    X[tl][dl] = v;
  }
  __syncthreads();
  const int tx = tid & 63;
  const int ty = tid >> 6;
#pragma unroll
  for (int i = 0; i < 16; ++i) {
    int dl = ty * 16 + i;
    float acc = Bi[dl];
#pragma unroll
    for (int j = 0; j < 4; ++j) acc = fmaf(Wl[dl * 4 + j], X[tx + j][dl], acc);
    xT[((size_t)(b * 1024 + d0 + dl)) * 1024 + t0 + tx] = silu_f(acc);
  }
}

// ---------------- xproj: x_dbl[m, c] = sum_d xT[d, m] * W[d, c] -------------
// wave per (m-tile of 64, c-quad); 1088 waves.
__global__ __launch_bounds__(256) void xproj_kernel(
    const float* __restrict__ xT, const float* __restrict__ WT,
    float* __restrict__ x_dbl) {
  const int tid = threadIdx.x;
  const int lane = tid & 63;
  const int w = blockIdx.x * 4 + (tid >> 6);  // 0..1087
  const int g = w % 34;
  const int mt = w / 34;                       // 0..31
  const int b = mt >> 4;
  const int t0 = (mt & 15) * 64;
  float a0 = 0.f, a1 = 0.f, a2 = 0.f, a3 = 0.f;
  const float* xbase = xT + ((size_t)b * 1024) * 1024 + t0 + lane;
  for (int kb = 0; kb < 16; ++kb) {
    float w0 = WT[(g * 4 + 0) * 1024 + kb * 64 + lane];
    float w1 = WT[(g * 4 + 1) * 1024 + kb * 64 + lane];
    float w2 = WT[(g * 4 + 2) * 1024 + kb * 64 + lane];
    float w3 = WT[(g * 4 + 3) * 1024 + kb * 64 + lane];
#pragma unroll
    for (int kk = 0; kk < 64; ++kk) {
      float xv = xbase[(size_t)(kb * 64 + kk) * 1024];
      a0 = fmaf(xv, readlane_f(w0, kk), a0);
      a1 = fmaf(xv, readlane_f(w1, kk), a1);
      a2 = fmaf(xv, readlane_f(w2, kk), a2);
      a3 = fmaf(xv, readlane_f(w3, kk), a3);
    }
  }
  size_t m = (size_t)(b * 1024 + t0 + lane);
  *(float4*)&x_dbl[m * 136 + g * 4] = make_float4(a0, a1, a2, a3);
}

// ---------------- dtproj: delta = softplus(dlow @ dtW + db), transposed -----
__global__ __launch_bounds__(256) void dtproj_kernel(
    const float* __restrict__ x_dbl, const float* __restrict__ dtW,
    const float* __restrict__ dtb, float* __restrict__ deltaT) {
  const int d = blockIdx.x;
  const int m = blockIdx.y * 256 + threadIdx.x;
  const int b = m >> 10, t = m & 1023;
  const float4 l0 = *(const float4*)&x_dbl[(size_t)m * 136 + 0];
  const float4 l1 = *(const float4*)&x_dbl[(size_t)m * 136 + 4];
  float acc = dtb[d];
  acc = fmaf(l0.x, dtW[0 * 1024 + d], acc);
  acc = fmaf(l0.y, dtW[1 * 1024 + d], acc);
  acc = fmaf(l0.z, dtW[2 * 1024 + d], acc);
  acc = fmaf(l0.w, dtW[3 * 1024 + d], acc);
  acc = fmaf(l1.x, dtW[4 * 1024 + d], acc);
  acc = fmaf(l1.y, dtW[5 * 1024 + d], acc);
  acc = fmaf(l1.z, dtW[6 * 1024 + d], acc);
  acc = fmaf(l1.w, dtW[7 * 1024 + d], acc);
  float sp = fmaxf(acc, 0.f) + log1pf(expf(-fabsf(acc)));
  deltaT[((size_t)(b * 1024 + d)) * 1024 + t] = sp;
}

// ---------------- scan: wave per (b,d), lane = n; y2T = scan_y + x*D --------
__global__ __launch_bounds__(256) void scan_kernel(
    const float* __restrict__ x_dbl, const float* __restrict__ deltaT,
    const float* __restrict__ xT, const float* __restrict__ A_log,
    const float* __restrict__ D_skip, float* __restrict__ y2T) {
  __shared__ float Bl[64][64];
  __shared__ float Cl[64][64];
  const int tid = threadIdx.x;
  const int lane = tid & 63;
  const int w = blockIdx.x * 4 + (tid >> 6);  // 0..2047 (4 waves share b)
  const int b = w >> 10, d = w & 1023;
  // A = -exp(A_log); pre-scale by log2(e) so dA = exp2(delta * a2)
  const float a2 = -__builtin_amdgcn_exp2f(A_log[d * 64 + lane] * LOG2E) * LOG2E;
  const float Dd = D_skip[d];
  const float* dptr = deltaT + ((size_t)(b * 1024 + d)) * 1024;
  const float* xptr = xT + ((size_t)(b * 1024 + d)) * 1024;
  const float* xdb = x_dbl + (size_t)(b * 1024) * 136;
  float h = 0.f;
  for (int t0 = 0; t0 < 1024; t0 += 64) {
    __syncthreads();
#pragma unroll
    for (int j = 0; j < 4; ++j) {
      int fidx = tid + j * 256;  // 0..1023
      int row = fidx >> 4, cq = fidx & 15;
      const float* rp = xdb + (size_t)(t0 + row) * 136;
      *(float4*)&Bl[row][cq * 4] = *(const float4*)(rp + 8 + cq * 4);
      *(float4*)&Cl[row][cq * 4] = *(const float4*)(rp + 72 + cq * 4);
    }
    float dv = dptr[t0 + lane];
    float xv = xptr[t0 + lane];
    __syncthreads();
    float ybuf = 0.f;
#pragma unroll
    for (int i = 0; i < 64; ++i) {
      float dt = readlane_f(dv, i);
      float xt = readlane_f(xv, i);
      float dA = __builtin_amdgcn_exp2f(dt * a2);
      float dBx = dt * xt * Bl[i][lane];
      h = fmaf(dA, h, dBx);
      float p = wave_sum64(h * Cl[i][lane]);
      float ysum = readlane_f(p, 63);
      float yfin = fmaf(xt, Dd, ysum);
      ybuf = (lane == i) ? yfin : ybuf;
    }
    y2T[((size_t)(b * 1024 + d)) * 1024 + t0 + lane] = ybuf;
  }
}

// ---------------- elemwise: u[m,d] = y2T^T * silu(z); u -> xz0[:, 0:1024] ---
__global__ __launch_bounds__(256) void elemwise_kernel(
    const float* __restrict__ y2T, float* __restrict__ xz0,
    const float* __restrict__ xz1) {
  __shared__ float Lts[64][65];
  const int tid = threadIdx.x;
  const int t0 = blockIdx.x * 64, d0 = blockIdx.y * 64, b = blockIdx.z;
  for (int idx = tid; idx < 4096; idx += 256) {
    int dl = idx >> 6, tl = idx & 63;
    Lts[tl][dl] = y2T[((size_t)(b * 1024 + d0 + dl)) * 1024 + t0 + tl];
  }
  __syncthreads();
  for (int idx = tid; idx < 4096; idx += 256) {
    int tl = idx >> 6, dl = idx & 63;
    size_t m = (size_t)(b * 1024 + t0 + tl);
    size_t oz = m * 2048 + 1024 + d0 + dl;
    float z = xz0[oz] + xz1[oz];
    xz0[m * 2048 + d0 + dl] = Lts[tl][dl] * silu_f(z);
  }
}

// ---------------- gemm_out: out[m, 0:512] = u[m, 0:1024] @ Wq2, K-split 4 ---
__global__ __launch_bounds__(128) void gemm_out_kernel(
    const float* __restrict__ U,  // xz0, row stride 2048, cols 0..1023
    const float* __restrict__ w0, const float* __restrict__ w1,
    const float* __restrict__ w2, const float* __restrict__ w3,
    float* __restrict__ outp) {
  __shared__ float As[16][128];
  __shared__ float Bs[16][64];
  const int tid = threadIdx.x;
  const int m0 = blockIdx.x * 128;
  const int n0 = blockIdx.y * 64;
  const int kbase = blockIdx.z * 256;
  const int oc = n0 >> 7;
  const int col0 = n0 & 127;
  const int tm = tid & 15, tn = tid >> 4;
  float acc[8][8] = {};
  for (int kc = 0; kc < 256; kc += 16) {
    const int k0 = kbase + kc;
    const int ic = k0 >> 8;
    const int kin = k0 & 255;
    const int wi = ic ^ oc;
    const float* W = (wi == 0) ? w0 : (wi == 1) ? w1 : (wi == 2) ? w2 : w3;
    const float sg = qsign(ic, oc);
#pragma unroll
    for (int j = 0; j < 4; ++j) {
      int fidx = tid + j * 128;
      int mm = fidx >> 2, kq = fidx & 3;
      const float4 v = *(const float4*)&U[(size_t)(m0 + mm) * 2048 + k0 + kq * 4];
      As[kq * 4 + 0][mm] = v.x; As[kq * 4 + 1][mm] = v.y;
      As[kq * 4 + 2][mm] = v.z; As[kq * 4 + 3][mm] = v.w;
    }
#pragma unroll
    for (int j = 0; j < 2; ++j) {
      int fidx = tid + j * 128;
      int kk = fidx >> 4, nq = fidx & 15;
      float4 v = *(const float4*)&W[(size_t)(kin + kk) * 128 + col0 + nq * 4];
      v.x *= sg; v.y *= sg; v.z *= sg; v.w *= sg;
      *(float4*)&Bs[kk][nq * 4] = v;
    }
    __syncthreads();
#pragma unroll
    for (int kk = 0; kk < 16; ++kk) {
      float a[8], bb[8];
      *(float4*)&a[0] = *(const float4*)&As[kk][tm * 8];
      *(float4*)&a[4] = *(const float4*)&As[kk][tm * 8 + 4];
      *(float4*)&bb[0] = *(const float4*)&Bs[kk][tn * 8];
      *(float4*)&bb[4] = *(const float4*)&Bs[kk][tn * 8 + 4];
#pragma unroll
      for (int u = 0; u < 8; ++u)
#pragma unroll
        for (int v = 0; v < 8; ++v) acc[u][v] = fmaf(a[u], bb[v], acc[u][v]);
    }
    __syncthreads();
  }
  float* dst = outp + (size_t)blockIdx.z * 1048576;
#pragma unroll
  for (int u = 0; u < 8; ++u) {
    size_t m = (size_t)(m0 + tm * 8 + u);
    *(float4*)&dst[m * 512 + n0 + tn * 8] =
        make_float4(acc[u][0], acc[u][1], acc[u][2], acc[u][3]);
    *(float4*)&dst[m * 512 + n0 + tn * 8 + 4] =
        make_float4(acc[u][4], acc[u][5], acc[u][6], acc[u][7]);
  }
}

// ---------------- addout: d_out = sum of 4 K-split partials -----------------
__global__ __launch_bounds__(256) void addout_kernel(const float* __restrict__ p,
                                                     float* __restrict__ o) {
  size_t i = ((size_t)blockIdx.x * 256 + threadIdx.x) * 4;
  float4 a = *(const float4*)&p[i];
  float4 b = *(const float4*)&p[1048576 + i];
  float4 c = *(const float4*)&p[2097152 + i];
  float4 d = *(const float4*)&p[3145728 + i];
  *(float4*)&o[i] = make_float4(a.x + b.x + c.x + d.x, a.y + b.y + c.y + d.y,
                                a.z + b.z + c.z + d.z, a.w + b.w + c.w + d.w);
}

// ---------------- launch ----------------------------------------------------
extern "C" void kernel_launch(void* const* d_in, const int* in_sizes, int n_in,
                              void* d_out, int out_size, void* d_ws, size_t ws_size,
                              hipStream_t stream) {
  (void)in_sizes; (void)n_in; (void)out_size;
  const float* q_r = (const float*)d_in[0];
  const float* q_i = (const float*)d_in[1];
  const float* q_j = (const float*)d_in[2];
  const float* q_k = (const float*)d_in[3];
  const float* in_Wr = (const float*)d_in[4];
  const float* in_Wi = (const float*)d_in[5];
  const float* in_Wj = (const float*)d_in[6];
  const float* in_Wk = (const float*)d_in[7];
  const float* conv_w = (const float*)d_in[8];
  const float* conv_b = (const float*)d_in[9];
  const float* xproj_W = (const float*)d_in[10];
  const float* dtproj_W = (const float*)d_in[11];
  const float* dtproj_b = (const float*)d_in[12];
  const float* A_log = (const float*)d_in[13];
  const float* D_skip = (const float*)d_in[14];
  const float* out_Wr = (const float*)d_in[15];
  const float* out_Wi = (const float*)d_in[16];
  const float* out_Wj = (const float*)d_in[17];
  const float* out_Wk = (const float*)d_in[18];

  float* ws = (float*)d_ws;
  // layout (floats): xz0 0 | xz1 4194304 | xT 8388608 | deltaT 10485760 |
  //                  y2T 12582912 | x_dbl 14680064 | WT 14958592 | end 15097856
  if (ws_size < (size_t)15097856 * 4) return;  // ws too small -> no-op
  float* xz0 = ws;
  float* xz1 = ws + 4194304;
  float* xT = ws + 8388608;
  float* deltaT = ws + 10485760;
  float* y2T = ws + 12582912;
  float* x_dbl = ws + 14680064;
  float* WT = ws + 14958592;
  float* outp = ws + 10485760;  // aliases deltaT+y2T (both dead by gemm_out)

  wtprep_kernel<<<dim3(136, 4), 256, 0, stream>>>(xproj_W, WT);
  gemm_in_kernel<<<dim3(16, 32, 2), 128, 0, stream>>>(
      q_r, q_i, q_j, q_k, in_Wr, in_Wi, in_Wj, in_Wk, xz0, xz1);
  conv_kernel<<<dim3(16, 16, 2), 256, 0, stream>>>(xz0, xz1, conv_w, conv_b, xT);
  xproj_kernel<<<dim3(272), 256, 0, stream>>>(xT, WT, x_dbl);
  dtproj_kernel<<<dim3(1024, 8), 256, 0, stream>>>(x_dbl, dtproj_W, dtproj_b, deltaT);
  scan_kernel<<<dim3(512), 256, 0, stream>>>(x_dbl, deltaT, xT, A_log, D_skip, y2T);
  elemwise_kernel<<<dim3(16, 16, 2), 256, 0, stream>>>(y2T, xz0, xz1);
  gemm_out_kernel<<<dim3(16, 8, 4), 128, 0, stream>>>(
      xz0, out_Wr, out_Wi, out_Wj, out_Wk, outp);
  addout_kernel<<<dim3(1024), 256, 0, stream>>>(outp, (float*)d_out);
}